// Round 8
// baseline (607.823 us; speedup 1.0000x reference)
//
#include <hip/hip_runtime.h>

typedef __attribute__((ext_vector_type(8))) short short8;
typedef __attribute__((ext_vector_type(4))) float f32x4;

#define SS 1024
#define NBLK 32    // lstm blocks (8 batch rows each: 2 groups of 4)
#define HROW 72    // bf16 elems per hbuf row (144 B, 16B-aligned)

__device__ __forceinline__ float sigmoidf_(float x) {
    return __builtin_amdgcn_rcpf(1.0f + __expf(-x));
}
__device__ __forceinline__ float tanhf_(float x) {
    return 1.0f - 2.0f * __builtin_amdgcn_rcpf(__expf(2.0f * x) + 1.0f);
}
__device__ __forceinline__ unsigned short f2bf(float f) {   // RNE f32->bf16
    unsigned int u = __float_as_uint(f);
    u += 0x7fffu + ((u >> 16) & 1u);
    return (unsigned short)(u >> 16);
}
__device__ __forceinline__ float bf2f(unsigned short u) {
    return __uint_as_float((unsigned int)u << 16);
}
__device__ __forceinline__ float h2f_lo(unsigned int u) {
    _Float16 h; unsigned short s = (unsigned short)(u & 0xffffu);
    __builtin_memcpy(&h, &s, 2); return (float)h;
}
__device__ __forceinline__ float h2f_hi(unsigned int u) {
    _Float16 h; unsigned short s = (unsigned short)(u >> 16);
    __builtin_memcpy(&h, &s, 2); return (float)h;
}
__device__ __forceinline__ unsigned int pkf16(float a, float b) {
    auto p = __builtin_amdgcn_cvt_pkrtz(a, b);   // __fp16 ext_vector(2)
    unsigned int u; __builtin_memcpy(&u, &p, 4); return u;
}

// lgkm-only barrier: global (vmcnt) prefetches/stores stay in flight.
#define RAW_BARRIER() asm volatile("s_waitcnt lgkmcnt(0)\n\ts_barrier" ::: "memory")

#define MF(A, Bv, C) __builtin_amdgcn_mfma_f32_16x16x32_bf16(A, Bv, C, 0, 0, 0)

// ============ Kernel 1: xz = x@W + bias, f16 gate-interleaved ==============
// Layout: xzp[(b*1024+t)*64 + n] = uint2{ pk(zi,zf), pk(zc,zo) }  (8 B).
// 1024 blocks x 4 waves; each wave does 4 tiles of 16 rows x 256 cols
// (4096 waves -> >=2 waves/SIMD so load/store latency is TLP-hidden).
__global__ __launch_bounds__(256)
void xzgemm(const float* __restrict__ x, const float* __restrict__ wk,
            const float* __restrict__ bias, uint2* __restrict__ xzp) {
    const int tid = threadIdx.x;
    const int l   = tid & 63;
    const int w   = tid >> 6;
    const int m   = l & 15;
    const int q   = l >> 4;

    short8 Bf[16][2];     // 16 col-tiles x 2 k-halves (static-indexed only)
    float  bv[16];
#pragma unroll
    for (int ct = 0; ct < 16; ++ct) {
        bv[ct] = bias[ct * 16 + m];
#pragma unroll
        for (int h2 = 0; h2 < 2; ++h2) {
            short8 v;
#pragma unroll
            for (int j = 0; j < 8; ++j)
                v[j] = (short)f2bf(wk[(h2 * 32 + q * 8 + j) * 256 + ct * 16 + m]);
            Bf[ct][h2] = v;
        }
    }

    const int wt = blockIdx.x * 4 + w;        // wave id 0..4095
    for (int it = 0; it < 4; ++it) {
        const int ti = wt * 4 + it;           // 16-row tile, 0..16383
        const float* __restrict__ xr = x + (size_t)(ti * 16 + m) * 64;
        const float4 a0 = *(const float4*)(xr + q * 8);
        const float4 a1 = *(const float4*)(xr + q * 8 + 4);
        const float4 b0 = *(const float4*)(xr + 32 + q * 8);
        const float4 b1 = *(const float4*)(xr + 32 + q * 8 + 4);
        short8 xa0, xa1;
        xa0[0] = (short)f2bf(a0.x); xa0[1] = (short)f2bf(a0.y);
        xa0[2] = (short)f2bf(a0.z); xa0[3] = (short)f2bf(a0.w);
        xa0[4] = (short)f2bf(a1.x); xa0[5] = (short)f2bf(a1.y);
        xa0[6] = (short)f2bf(a1.z); xa0[7] = (short)f2bf(a1.w);
        xa1[0] = (short)f2bf(b0.x); xa1[1] = (short)f2bf(b0.y);
        xa1[2] = (short)f2bf(b0.z); xa1[3] = (short)f2bf(b0.w);
        xa1[4] = (short)f2bf(b1.x); xa1[5] = (short)f2bf(b1.y);
        xa1[6] = (short)f2bf(b1.z); xa1[7] = (short)f2bf(b1.w);

#pragma unroll
        for (int ctn = 0; ctn < 4; ++ctn) {   // n-block; gates from ct=ctn+4g
            const f32x4 ci = {bv[ctn],      bv[ctn],      bv[ctn],      bv[ctn]};
            const f32x4 cf = {bv[ctn + 4],  bv[ctn + 4],  bv[ctn + 4],  bv[ctn + 4]};
            const f32x4 cc = {bv[ctn + 8],  bv[ctn + 8],  bv[ctn + 8],  bv[ctn + 8]};
            const f32x4 co = {bv[ctn + 12], bv[ctn + 12], bv[ctn + 12], bv[ctn + 12]};
            const f32x4 zi = MF(xa1, Bf[ctn][1],      MF(xa0, Bf[ctn][0],      ci));
            const f32x4 zf = MF(xa1, Bf[ctn + 4][1],  MF(xa0, Bf[ctn + 4][0],  cf));
            const f32x4 zc = MF(xa1, Bf[ctn + 8][1],  MF(xa0, Bf[ctn + 8][0],  cc));
            const f32x4 zo = MF(xa1, Bf[ctn + 12][1], MF(xa0, Bf[ctn + 12][0], co));
            uint2* __restrict__ ob =
                xzp + ((size_t)(ti * 16 + q * 4) * 64 + ctn * 16 + m);
#pragma unroll
            for (int r = 0; r < 4; ++r) {
                uint2 v;
                v.x = pkf16(zi[r], zf[r]);
                v.y = pkf16(zc[r], zo[r]);
                ob[(size_t)r * 64] = v;
            }
        }
    }
}

// ============ Kernel 2: dual-recurrence 4-row sparse-A LSTM ================
// 32 blocks x 4 waves; each block owns 8 batch rows = 2 independent groups
// (A: rows bb*8+q, B: rows bb*8+4+q). Both groups step together per barrier
// phase; group B's independent MFMAs/gates fill group A's latency gaps.
// Sparse map: batch row b -> A-row 4b; lane (q,m) computes 1 gate set per
// group (batch q, col n0) from z reg 0. xz (dwordx2/step) is the C-init.
// h streams to global (bf16); dense output is a separate trivial kernel.
#define LOADB(VAR, G, KC) do {                                                \
    const int kb = ((KC) << 5) + (q << 3);                                    \
    const int nn = ((G) << 6) + n0;                                           \
    short8 v;                                                                 \
    v[0] = (short)f2bf(rk[(kb + 0) * 256 + nn]);                              \
    v[1] = (short)f2bf(rk[(kb + 1) * 256 + nn]);                              \
    v[2] = (short)f2bf(rk[(kb + 2) * 256 + nn]);                              \
    v[3] = (short)f2bf(rk[(kb + 3) * 256 + nn]);                              \
    v[4] = (short)f2bf(rk[(kb + 4) * 256 + nn]);                              \
    v[5] = (short)f2bf(rk[(kb + 5) * 256 + nn]);                              \
    v[6] = (short)f2bf(rk[(kb + 6) * 256 + nn]);                              \
    v[7] = (short)f2bf(rk[(kb + 7) * 256 + nn]);                              \
    VAR = v; } while (0)

// One phase = one timestep for BOTH groups, one barrier.
#define REGION2(T, PAR, Pa, Pb) do {                                           \
    const short8 a0 = *(const short8*)&hbufA[(PAR) ^ 1][m * HROW + (q << 3)];  \
    const short8 a1 = *(const short8*)&hbufA[(PAR) ^ 1][m * HROW + 32 + (q << 3)]; \
    const short8 b0 = *(const short8*)&hbufB[(PAR) ^ 1][m * HROW + (q << 3)];  \
    const short8 b1 = *(const short8*)&hbufB[(PAR) ^ 1][m * HROW + 32 + (q << 3)]; \
    const uint2 curA = Pa; const uint2 curB = Pb;                              \
    { const size_t xo = (size_t)(((T) + 2 < SS) ? (T) + 2 : SS - 1) << 6;      \
      Pa = xbA[xo]; Pb = xbB[xo]; }                                            \
    const float viA = h2f_lo(curA.x), vfA = h2f_hi(curA.x);                    \
    const float vcA = h2f_lo(curA.y), voA = h2f_hi(curA.y);                    \
    const float viB = h2f_lo(curB.x), vfB = h2f_hi(curB.x);                    \
    const float vcB = h2f_lo(curB.y), voB = h2f_hi(curB.y);                    \
    const f32x4 cgcA = {vcA, vcA, vcA, vcA};                                   \
    const f32x4 cgoA = {voA, voA, voA, voA};                                   \
    const f32x4 cgiA = {viA, viA, viA, viA};                                   \
    const f32x4 cgfA = {vfA, vfA, vfA, vfA};                                   \
    const f32x4 cgcB = {vcB, vcB, vcB, vcB};                                   \
    const f32x4 cgoB = {voB, voB, voB, voB};                                   \
    const f32x4 cgiB = {viB, viB, viB, viB};                                   \
    const f32x4 cgfB = {vfB, vfB, vfB, vfB};                                   \
    const f32x4 zcA = MF(a1, BHC1, MF(a0, BHC0, cgcA));                        \
    const f32x4 zcB = MF(b1, BHC1, MF(b0, BHC0, cgcB));                        \
    const f32x4 zoA = MF(a1, BHO1, MF(a0, BHO0, cgoA));                        \
    const f32x4 zoB = MF(b1, BHO1, MF(b0, BHO0, cgoB));                        \
    const f32x4 ziA = MF(a1, BHI1, MF(a0, BHI0, cgiA));                        \
    const f32x4 ziB = MF(b1, BHI1, MF(b0, BHI0, cgiB));                        \
    const f32x4 zfA = MF(a1, BHF1, MF(a0, BHF0, cgfA));                        \
    const f32x4 zfB = MF(b1, BHF1, MF(b0, BHF0, cgfB));                        \
    const float tcA = tanhf_(zcA[0]);                                          \
    const float tcB = tanhf_(zcB[0]);                                          \
    const float goA = sigmoidf_(zoA[0]), giA = sigmoidf_(ziA[0]);              \
    const float gfA = sigmoidf_(zfA[0]);                                       \
    const float goB = sigmoidf_(zoB[0]), giB = sigmoidf_(ziB[0]);              \
    const float gfB = sigmoidf_(zfB[0]);                                       \
    ccA = gfA * ccA + giA * tcA;                                               \
    ccB = gfB * ccB + giB * tcB;                                               \
    const float hA = goA * tanhf_(ccA);                                        \
    const float hB = goB * tanhf_(ccB);                                        \
    const unsigned short hA16 = f2bf(hA), hB16 = f2bf(hB);                     \
    hbufA[PAR][(q << 2) * HROW + n0] = (short)hA16;                            \
    hbufB[PAR][(q << 2) * HROW + n0] = (short)hB16;                            \
    hbA[(size_t)(T) << 6] = hA16;                                              \
    hbB[(size_t)(T) << 6] = hB16;                                              \
    RAW_BARRIER();                                                             \
} while (0)

__global__ __launch_bounds__(256, 1)
void lstm_g2(const uint2* __restrict__ xzu, const float* __restrict__ rk,
             unsigned short* __restrict__ hg) {
    const int bb  = blockIdx.x;               // 0..31, 8 batch rows each
    const int tid = threadIdx.x;
    const int l   = tid & 63;
    const int w   = tid >> 6;
    const int m   = l & 15;
    const int q   = l >> 4;
    const int n0  = (w << 4) + m;

    __shared__ short hbufA[2][16 * HROW];     // 4.6 KB each, double-buffered
    __shared__ short hbufB[2][16 * HROW];

    for (int i = tid; i < 2 * 16 * HROW; i += 256) {
        ((short*)hbufA)[i] = 0;
        ((short*)hbufB)[i] = 0;
    }
    __syncthreads();

    short8 BHI0, BHI1, BHF0, BHF1, BHC0, BHC1, BHO0, BHO1;
    LOADB(BHI0, 0, 0); LOADB(BHI1, 0, 1);
    LOADB(BHF0, 1, 0); LOADB(BHF1, 1, 1);
    LOADB(BHC0, 2, 0); LOADB(BHC1, 2, 1);
    LOADB(BHO0, 3, 0); LOADB(BHO1, 3, 1);

    // Per-lane bases: row (b*1024+t), elem n0 -> idx = (b<<16)+(t<<6)+n0.
    const size_t baseA = ((size_t)((bb << 3) + q) << 16) + n0;
    const size_t baseB = ((size_t)((bb << 3) + 4 + q) << 16) + n0;
    const uint2* __restrict__ xbA = xzu + baseA;
    const uint2* __restrict__ xbB = xzu + baseB;
    unsigned short* __restrict__ hbA = hg + baseA;
    unsigned short* __restrict__ hbB = hg + baseB;

    uint2 QA = xbA[0], RA = xbA[64];          // t=0 / t=1 prefetch, group A
    uint2 QB = xbB[0], RB = xbB[64];          // group B
    float ccA = 0.f, ccB = 0.f;

    REGION2(0, 0, QA, QB);
    REGION2(1, 1, RA, RB);
    for (int t = 2; t < SS; t += 2) {
        REGION2(t,     0, QA, QB);
        REGION2(t + 1, 1, RA, RB);
    }
}

// ============ Kernel 3: out = sigmoid(h @ dw + db), one thread per (b,t) ===
__global__ __launch_bounds__(256)
void dense_out(const unsigned short* __restrict__ hg,
               const float* __restrict__ dw, const float* __restrict__ db,
               float* __restrict__ out) {
    const int row = blockIdx.x * 256 + threadIdx.x;    // b*1024 + t
    const short8* __restrict__ hr = (const short8*)(hg + (size_t)row * 64);
    float acc = db[0];
#pragma unroll
    for (int jj = 0; jj < 8; ++jj) {
        const short8 v = hr[jj];
#pragma unroll
        for (int k = 0; k < 8; ++k)
            acc += bf2f((unsigned short)v[k]) * dw[jj * 8 + k];
    }
    out[row] = sigmoidf_(acc);
}

// ============ Host ============
extern "C" void kernel_launch(void* const* d_in, const int* in_sizes, int n_in,
                              void* d_out, int out_size, void* d_ws, size_t ws_size,
                              hipStream_t stream) {
    const float* x    = (const float*)d_in[0];
    const float* wk   = (const float*)d_in[1];
    const float* rk   = (const float*)d_in[2];
    const float* bias = (const float*)d_in[3];
    const float* dw   = (const float*)d_in[4];
    const float* db   = (const float*)d_in[5];
    float* out = (float*)d_out;

    const size_t XZ_BYTES = (size_t)262144 * 256 * 2;  // 128 MB
    uint2* xz = (uint2*)d_ws;
    unsigned short* hg = (unsigned short*)((char*)d_ws + XZ_BYTES); // 32 MB

    hipLaunchKernelGGL(xzgemm, dim3(1024), dim3(256), 0, stream,
                       x, wk, bias, xz);
    hipLaunchKernelGGL(lstm_g2, dim3(NBLK), dim3(256), 0, stream,
                       xz, rk, hg);
    hipLaunchKernelGGL(dense_out, dim3(1024), dim3(256), 0, stream,
                       hg, dw, db, out);
}

// Round 9
// 457.275 us; speedup vs baseline: 1.3292x; 1.3292x over previous
//
#include <hip/hip_runtime.h>

typedef __attribute__((ext_vector_type(8))) short short8;
typedef __attribute__((ext_vector_type(4))) float f32x4;

#define SS 1024
#define NBLK 64    // lstm blocks (4 batch rows each)
#define HROW 72    // bf16 elems per hbuf row (144 B, 16B-aligned)

__device__ __forceinline__ float sigmoidf_(float x) {
    return __builtin_amdgcn_rcpf(1.0f + __expf(-x));
}
__device__ __forceinline__ float tanhf_(float x) {
    return 1.0f - 2.0f * __builtin_amdgcn_rcpf(__expf(2.0f * x) + 1.0f);
}
__device__ __forceinline__ unsigned short f2bf(float f) {   // RNE f32->bf16
    unsigned int u = __float_as_uint(f);
    u += 0x7fffu + ((u >> 16) & 1u);
    return (unsigned short)(u >> 16);
}
__device__ __forceinline__ float bf2f(unsigned short u) {
    return __uint_as_float((unsigned int)u << 16);
}
__device__ __forceinline__ float h2f_lo(unsigned int u) {
    _Float16 h; unsigned short s = (unsigned short)(u & 0xffffu);
    __builtin_memcpy(&h, &s, 2); return (float)h;
}
__device__ __forceinline__ float h2f_hi(unsigned int u) {
    _Float16 h; unsigned short s = (unsigned short)(u >> 16);
    __builtin_memcpy(&h, &s, 2); return (float)h;
}
__device__ __forceinline__ unsigned int pkf16(float a, float b) {
    auto p = __builtin_amdgcn_cvt_pkrtz(a, b);   // __fp16 ext_vector(2)
    unsigned int u; __builtin_memcpy(&u, &p, 4); return u;
}

// lgkm-only barrier: global (vmcnt) prefetches/stores stay in flight.
#define RAW_BARRIER() asm volatile("s_waitcnt lgkmcnt(0)\n\ts_barrier" ::: "memory")

#define MF(A, Bv, C) __builtin_amdgcn_mfma_f32_16x16x32_bf16(A, Bv, C, 0, 0, 0)

// ============ Kernel 1: fused producer/consumer LSTM =======================
// 64 blocks x 8 waves. Waves 0-3: recurrence consumer (round-6 structure).
// Waves 4-7: xz producer -- per phase computes xz(t+1) = x(t+1)@W + bias for
// this block's 4 batch rows via 8 MFMAs, packs f16 gate-interleaved uint2,
// writes a 2-slot LDS ring. Slot written in phase t is read in phase t+1.
// Producer issue (~150cy) hides inside consumer phase (~670cy) via separate-
// wave co-scheduling; the 128 MB xz HBM round-trip is eliminated.
// Sparse map: batch b -> A-rows 4b..4b+3 (dup); C reg0 row 4q = batch q.

#define LOADB(VAR, G, KC, SRC, NN) do {                                       \
    const int kb = ((KC) << 5) + (q << 3);                                    \
    short8 v;                                                                 \
    v[0] = (short)f2bf(SRC[(kb + 0) * 256 + (NN)]);                           \
    v[1] = (short)f2bf(SRC[(kb + 1) * 256 + (NN)]);                           \
    v[2] = (short)f2bf(SRC[(kb + 2) * 256 + (NN)]);                           \
    v[3] = (short)f2bf(SRC[(kb + 3) * 256 + (NN)]);                           \
    v[4] = (short)f2bf(SRC[(kb + 4) * 256 + (NN)]);                           \
    v[5] = (short)f2bf(SRC[(kb + 5) * 256 + (NN)]);                           \
    v[6] = (short)f2bf(SRC[(kb + 6) * 256 + (NN)]);                           \
    v[7] = (short)f2bf(SRC[(kb + 7) * 256 + (NN)]);                           \
    VAR = v; } while (0)

// -------- consumer phase: one timestep --------
#define CREGION(T, PAR) do {                                                   \
    const short8 ha0 = *(const short8*)&hbuf[(PAR) ^ 1][m * HROW + (q << 3)];  \
    const short8 ha1 = *(const short8*)&hbuf[(PAR) ^ 1][m * HROW + 32 + (q << 3)]; \
    const uint2 cur = ring[(T) & 1][q][n0];                                    \
    const float vi = h2f_lo(cur.x), vf = h2f_hi(cur.x);                        \
    const float vc = h2f_lo(cur.y), vo = h2f_hi(cur.y);                        \
    const f32x4 cgc = {vc, vc, vc, vc};                                        \
    const f32x4 cgo = {vo, vo, vo, vo};                                        \
    const f32x4 cgi = {vi, vi, vi, vi};                                        \
    const f32x4 cgf = {vf, vf, vf, vf};                                        \
    const f32x4 zc = MF(ha1, BHC1, MF(ha0, BHC0, cgc));                        \
    const f32x4 zo = MF(ha1, BHO1, MF(ha0, BHO0, cgo));                        \
    const f32x4 zi = MF(ha1, BHI1, MF(ha0, BHI0, cgi));                        \
    const f32x4 zf = MF(ha1, BHF1, MF(ha0, BHF0, cgf));                        \
    const float tc = tanhf_(zc[0]);                                            \
    const float go = sigmoidf_(zo[0]);                                         \
    const float gi = sigmoidf_(zi[0]);                                         \
    const float gf = sigmoidf_(zf[0]);                                         \
    cc0 = gf * cc0 + gi * tc;                                                  \
    const float h0 = go * tanhf_(cc0);                                         \
    const unsigned short hb16 = f2bf(h0);                                      \
    hbuf[PAR][(q << 2) * HROW + n0] = (short)hb16;                             \
    hb[(size_t)(T) << 6] = hb16;                                               \
    RAW_BARRIER();                                                             \
} while (0)

// -------- producer phase: make xz(S) into ring[S&1]; refill x(S+2) --------
#define PPROD(S, RPS, F0, F1, F2, F3) do {                                     \
    if ((S) < SS) {                                                            \
        short8 xa0, xa1;                                                       \
        xa0[0] = (short)f2bf(F0.x); xa0[1] = (short)f2bf(F0.y);                \
        xa0[2] = (short)f2bf(F0.z); xa0[3] = (short)f2bf(F0.w);                \
        xa0[4] = (short)f2bf(F1.x); xa0[5] = (short)f2bf(F1.y);                \
        xa0[6] = (short)f2bf(F1.z); xa0[7] = (short)f2bf(F1.w);                \
        xa1[0] = (short)f2bf(F2.x); xa1[1] = (short)f2bf(F2.y);                \
        xa1[2] = (short)f2bf(F2.z); xa1[3] = (short)f2bf(F2.w);                \
        xa1[4] = (short)f2bf(F3.x); xa1[5] = (short)f2bf(F3.y);                \
        xa1[6] = (short)f2bf(F3.z); xa1[7] = (short)f2bf(F3.w);                \
        const f32x4 zi = MF(xa1, WI1, MF(xa0, WI0, cbi));                      \
        const f32x4 zf = MF(xa1, WF1, MF(xa0, WF0, cbf));                      \
        const f32x4 zc = MF(xa1, WC1, MF(xa0, WC0, cbc));                      \
        const f32x4 zo = MF(xa1, WO1, MF(xa0, WO0, cbo));                      \
        uint2 v;                                                               \
        v.x = pkf16(zi[0], zf[0]);                                             \
        v.y = pkf16(zc[0], zo[0]);                                             \
        ring[RPS][q][pw16m] = v;                                               \
    }                                                                          \
    { const int sn = ((S) + 2 < SS) ? (S) + 2 : SS - 1;                        \
      const float* __restrict__ xs = xp + ((size_t)sn << 6);                   \
      F0 = *(const float4*)(xs + (q << 3));                                    \
      F1 = *(const float4*)(xs + (q << 3) + 4);                                \
      F2 = *(const float4*)(xs + 32 + (q << 3));                               \
      F3 = *(const float4*)(xs + 36 + (q << 3)); }                             \
    RAW_BARRIER();                                                             \
} while (0)

__global__ __launch_bounds__(512, 1)
void lstm_fused(const float* __restrict__ x, const float* __restrict__ wk,
                const float* __restrict__ rk, const float* __restrict__ bias,
                unsigned short* __restrict__ hg) {
    const int bb  = blockIdx.x;               // 0..63, 4 batch rows each
    const int tid = threadIdx.x;
    const int l   = tid & 63;
    const int w   = tid >> 6;                 // 0-3 consumer, 4-7 producer
    const int m   = l & 15;
    const int q   = l >> 4;

    __shared__ short hbuf[2][16 * HROW];      // 4.6 KB, double-buffered h
    __shared__ uint2 ring[2][4][64];          // 4 KB, 2-slot xz ring

    for (int i = tid; i < 2 * 16 * HROW; i += 512) ((short*)hbuf)[i] = 0;
    __syncthreads();

    if (w < 4) {
        // ---------------- consumer: recurrence ----------------
        const int n0 = (w << 4) + m;
        short8 BHI0, BHI1, BHF0, BHF1, BHC0, BHC1, BHO0, BHO1;
        LOADB(BHI0, 0, 0, rk, (0 << 6) + n0); LOADB(BHI1, 0, 1, rk, (0 << 6) + n0);
        LOADB(BHF0, 1, 0, rk, (1 << 6) + n0); LOADB(BHF1, 1, 1, rk, (1 << 6) + n0);
        LOADB(BHC0, 2, 0, rk, (2 << 6) + n0); LOADB(BHC1, 2, 1, rk, (2 << 6) + n0);
        LOADB(BHO0, 3, 0, rk, (3 << 6) + n0); LOADB(BHO1, 3, 1, rk, (3 << 6) + n0);

        unsigned short* __restrict__ hb =
            hg + ((size_t)((bb << 2) + q) << 16) + n0;
        float cc0 = 0.f;

        RAW_BARRIER();                        // warm-up phase (producer makes t=0)
        for (int t = 0; t < SS; t += 2) {
            CREGION(t,     0);
            CREGION(t + 1, 1);
        }
    } else {
        // ---------------- producer: xz GEMM ----------------
        const int pw16m = ((w - 4) << 4) + m;
        short8 WI0, WI1, WF0, WF1, WC0, WC1, WO0, WO1;
        LOADB(WI0, 0, 0, wk, (0 << 6) + pw16m); LOADB(WI1, 0, 1, wk, (0 << 6) + pw16m);
        LOADB(WF0, 1, 0, wk, (1 << 6) + pw16m); LOADB(WF1, 1, 1, wk, (1 << 6) + pw16m);
        LOADB(WC0, 2, 0, wk, (2 << 6) + pw16m); LOADB(WC1, 2, 1, wk, (2 << 6) + pw16m);
        LOADB(WO0, 3, 0, wk, (3 << 6) + pw16m); LOADB(WO1, 3, 1, wk, (3 << 6) + pw16m);

        const float bi = bias[(0 << 6) + pw16m];
        const float bf = bias[(1 << 6) + pw16m];
        const float bc = bias[(2 << 6) + pw16m];
        const float bo = bias[(3 << 6) + pw16m];
        const f32x4 cbi = {bi, bi, bi, bi};
        const f32x4 cbf = {bf, bf, bf, bf};
        const f32x4 cbc = {bc, bc, bc, bc};
        const f32x4 cbo = {bo, bo, bo, bo};

        // A-row m <- batch (m>>2) of this block (x4 duplicated rows)
        const float* __restrict__ xp =
            x + ((size_t)((bb << 2) + (m >> 2)) << 16);   // *1024*64

        float4 XA0 = *(const float4*)(xp + (q << 3));
        float4 XA1 = *(const float4*)(xp + (q << 3) + 4);
        float4 XA2 = *(const float4*)(xp + 32 + (q << 3));
        float4 XA3 = *(const float4*)(xp + 36 + (q << 3));
        float4 XB0 = *(const float4*)(xp + 64 + (q << 3));
        float4 XB1 = *(const float4*)(xp + 64 + (q << 3) + 4);
        float4 XB2 = *(const float4*)(xp + 96 + (q << 3));
        float4 XB3 = *(const float4*)(xp + 100 + (q << 3));

        PPROD(0, 0, XA0, XA1, XA2, XA3);      // warm-up: xz(0) -> ring[0]
        for (int t = 0; t < SS; t += 2) {
            PPROD(t + 1, 1, XB0, XB1, XB2, XB3);
            PPROD(t + 2, 0, XA0, XA1, XA2, XA3);
        }
    }
}

// ============ Kernel 2: out = sigmoid(h @ dw + db), one thread per (b,t) ===
__global__ __launch_bounds__(256)
void dense_out(const unsigned short* __restrict__ hg,
               const float* __restrict__ dw, const float* __restrict__ db,
               float* __restrict__ out) {
    const int row = blockIdx.x * 256 + threadIdx.x;    // b*1024 + t
    const short8* __restrict__ hr = (const short8*)(hg + (size_t)row * 64);
    float acc = db[0];
#pragma unroll
    for (int jj = 0; jj < 8; ++jj) {
        const short8 v = hr[jj];
#pragma unroll
        for (int k = 0; k < 8; ++k)
            acc += bf2f((unsigned short)v[k]) * dw[jj * 8 + k];
    }
    out[row] = sigmoidf_(acc);
}

// ============ Host ============
extern "C" void kernel_launch(void* const* d_in, const int* in_sizes, int n_in,
                              void* d_out, int out_size, void* d_ws, size_t ws_size,
                              hipStream_t stream) {
    const float* x    = (const float*)d_in[0];
    const float* wk   = (const float*)d_in[1];
    const float* rk   = (const float*)d_in[2];
    const float* bias = (const float*)d_in[3];
    const float* dw   = (const float*)d_in[4];
    const float* db   = (const float*)d_in[5];
    float* out = (float*)d_out;

    unsigned short* hg = (unsigned short*)d_ws;        // 32 MB h stream

    hipLaunchKernelGGL(lstm_fused, dim3(NBLK), dim3(512), 0, stream,
                       x, wk, rk, bias, hg);
    hipLaunchKernelGGL(dense_out, dim3(1024), dim3(256), 0, stream,
                       hg, dw, db, out);
}